// Round 1
// baseline (492.871 us; speedup 1.0000x reference)
//
#include <hip/hip_runtime.h>
#include <cmath>

typedef unsigned short u16;
typedef __bf16 bf16x8 __attribute__((ext_vector_type(8)));
typedef float f32x4 __attribute__((ext_vector_type(4)));
typedef float float4v __attribute__((ext_vector_type(4)));
typedef u16 ushort4v __attribute__((ext_vector_type(4)));
typedef u16 ushort8v __attribute__((ext_vector_type(8)));

// ---------------- constants ----------------
#define DIMC 768
#define BC 32
#define NP 196            // 14*14
#define MTOT 6272         // 32*196
#define HIDC 3072
#define LAMC 3.5f

__device__ const float C14d[14] = {
  1.0f, 0.9009688679024191f, 0.6234898018587336f, 0.22252093395631445f,
  -0.22252093395631445f, -0.6234898018587336f, -0.9009688679024191f, -1.0f,
  -0.9009688679024191f, -0.6234898018587336f, -0.22252093395631445f,
  0.22252093395631445f, 0.6234898018587336f, 0.9009688679024191f
};
__device__ const float S14d[14] = {
  0.0f, 0.43388373911755823f, 0.7818314824680298f, 0.9749279121818236f,
  0.9749279121818236f, 0.7818314824680298f, 0.43388373911755823f, 0.0f,
  -0.43388373911755823f, -0.7818314824680298f, -0.9749279121818236f,
  -0.9749279121818236f, -0.7818314824680298f, -0.43388373911755823f
};

__device__ __forceinline__ u16 f2bf(float f) {
  unsigned u = __builtin_bit_cast(unsigned, f);
  unsigned r = u + 0x7FFFu + ((u >> 16) & 1u);
  return (u16)(r >> 16);
}

// ---------------- fp32 -> bf16 convert ----------------
__global__ __launch_bounds__(256) void cvt_k(const float* __restrict__ s,
                                             u16* __restrict__ d, int n) {
  int i = blockIdx.x * 256 + threadIdx.x;
  if (i < n) d[i] = f2bf(s[i]);
}

// ---------------- generic bf16-MFMA GEMM: C = epi(A * B^T) ----------------
// ASRC: 0 = A f32 raw; 1 = A f32, per-k a*scale[k]+shift[k]; 2 = A bf16
// EPI : 0 = transpose-write f32 to vx_t[(b*768+n)*196+np]  (m = b*196+np)
//       1 = f32: C[m*Nr+n] = acc + bias[n] + res[m*Nr+n]
//       2 = bf16: C[m*Nr+n] = gelu_exact(acc + bias[n])
#define TSV 36
template<int ASRC, int EPI>
__global__ __launch_bounds__(256) void gemm_k(
    const void* __restrict__ Ap, const u16* __restrict__ Bw,
    const float* __restrict__ scale, const float* __restrict__ shift,
    const float* __restrict__ bias, const float* __restrict__ res,
    void* __restrict__ Cp, int Nr, int Kr) {
  __shared__ u16 As[64 * TSV];
  __shared__ u16 Bs[64 * TSV];
  const int t = threadIdx.x;
  const int bn = blockIdx.x * 64, bm = blockIdx.y * 64;
  const int wid = t >> 6, lane = t & 63;
  const int wm = (wid >> 1) * 32, wn = (wid & 1) * 32;
  const int trow = t >> 2, tcol = (t & 3) * 8;
  const int l15 = lane & 15, l4 = lane >> 4;

  f32x4 acc[2][2];
#pragma unroll
  for (int a = 0; a < 2; ++a)
#pragma unroll
    for (int b2 = 0; b2 < 2; ++b2) acc[a][b2] = (f32x4){0.f, 0.f, 0.f, 0.f};

  for (int k0 = 0; k0 < Kr; k0 += 32) {
    ushort8v av;
    if (ASRC == 2) {
      av = *(const ushort8v*)((const u16*)Ap + (size_t)(bm + trow) * Kr + k0 + tcol);
    } else {
      const float* ap = (const float*)Ap + (size_t)(bm + trow) * Kr + k0 + tcol;
      float4v f0 = *(const float4v*)ap;
      float4v f1 = *(const float4v*)(ap + 4);
      if (ASRC == 1) {
        float4v s0 = *(const float4v*)(scale + k0 + tcol);
        float4v s1 = *(const float4v*)(scale + k0 + tcol + 4);
        float4v h0 = *(const float4v*)(shift + k0 + tcol);
        float4v h1 = *(const float4v*)(shift + k0 + tcol + 4);
        f0 = f0 * s0 + h0;
        f1 = f1 * s1 + h1;
      }
#pragma unroll
      for (int j = 0; j < 4; ++j) { av[j] = f2bf(f0[j]); av[j + 4] = f2bf(f1[j]); }
    }
    ushort8v bv = *(const ushort8v*)(Bw + (size_t)(bn + trow) * Kr + k0 + tcol);
    *(ushort4v*)&As[trow * TSV + tcol]     = __builtin_shufflevector(av, av, 0, 1, 2, 3);
    *(ushort4v*)&As[trow * TSV + tcol + 4] = __builtin_shufflevector(av, av, 4, 5, 6, 7);
    *(ushort4v*)&Bs[trow * TSV + tcol]     = __builtin_shufflevector(bv, bv, 0, 1, 2, 3);
    *(ushort4v*)&Bs[trow * TSV + tcol + 4] = __builtin_shufflevector(bv, bv, 4, 5, 6, 7);
    __syncthreads();

    bf16x8 af[2], bfr[2];
#pragma unroll
    for (int mb = 0; mb < 2; ++mb) {
      int row = wm + mb * 16 + l15;
      ushort4v lo = *(const ushort4v*)&As[row * TSV + l4 * 8];
      ushort4v hi = *(const ushort4v*)&As[row * TSV + l4 * 8 + 4];
      af[mb] = __builtin_bit_cast(bf16x8, __builtin_shufflevector(lo, hi, 0, 1, 2, 3, 4, 5, 6, 7));
    }
#pragma unroll
    for (int nb = 0; nb < 2; ++nb) {
      int row = wn + nb * 16 + l15;
      ushort4v lo = *(const ushort4v*)&Bs[row * TSV + l4 * 8];
      ushort4v hi = *(const ushort4v*)&Bs[row * TSV + l4 * 8 + 4];
      bfr[nb] = __builtin_bit_cast(bf16x8, __builtin_shufflevector(lo, hi, 0, 1, 2, 3, 4, 5, 6, 7));
    }
#pragma unroll
    for (int mb = 0; mb < 2; ++mb)
#pragma unroll
      for (int nb = 0; nb < 2; ++nb)
        acc[mb][nb] = __builtin_amdgcn_mfma_f32_16x16x32_bf16(af[mb], bfr[nb], acc[mb][nb], 0, 0, 0);
    __syncthreads();
  }

#pragma unroll
  for (int mb = 0; mb < 2; ++mb) {
#pragma unroll
    for (int nb = 0; nb < 2; ++nb) {
      int n = bn + wn + nb * 16 + l15;
#pragma unroll
      for (int r = 0; r < 4; ++r) {
        int m = bm + wm + mb * 16 + l4 * 4 + r;
        float v = acc[mb][nb][r];
        if (EPI == 0) {
          int bb = m / 196, np = m - bb * 196;
          ((float*)Cp)[((size_t)bb * DIMC + n) * 196 + np] = v;
        } else if (EPI == 1) {
          ((float*)Cp)[(size_t)m * Nr + n] = v + bias[n] + res[(size_t)m * Nr + n];
        } else {
          float vb = v + bias[n];
          float ge = 0.5f * vb * (1.f + erff(vb * 0.70710678118654752f));
          ((u16*)Cp)[(size_t)m * Nr + n] = f2bf(ge);
        }
      }
    }
  }
}

// ---------------- BN stats (deterministic 2-stage) ----------------
__global__ __launch_bounds__(256) void stats_part_k(const float* __restrict__ A,
                                                    float* __restrict__ part) {
  int blk = blockIdx.x, t = threadIdx.x;
  float s0a = 0, s0b = 0, s0c = 0, s1a = 0, s1b = 0, s1c = 0;
  const float* base = A + (size_t)blk * 64 * DIMC;
  for (int r = 0; r < 64; ++r) {
    const float* row = base + (size_t)r * DIMC;
    float v0 = row[t], v1 = row[t + 256], v2 = row[t + 512];
    s0a += v0; s1a += v0 * v0;
    s0b += v1; s1b += v1 * v1;
    s0c += v2; s1c += v2 * v2;
  }
  part[(size_t)blk * DIMC + t] = s0a;
  part[(size_t)blk * DIMC + t + 256] = s0b;
  part[(size_t)blk * DIMC + t + 512] = s0c;
  float* p2 = part + 98 * DIMC;
  p2[(size_t)blk * DIMC + t] = s1a;
  p2[(size_t)blk * DIMC + t + 256] = s1b;
  p2[(size_t)blk * DIMC + t + 512] = s1c;
}

__global__ __launch_bounds__(256) void stats_fin_k(const float* __restrict__ part,
    const float* __restrict__ gam, const float* __restrict__ bet,
    float* __restrict__ scale, float* __restrict__ shift) {
  int c = blockIdx.x * 256 + threadIdx.x;
  if (c >= DIMC) return;
  float S = 0.f, Q = 0.f;
  for (int b = 0; b < 98; ++b) {
    S += part[(size_t)b * DIMC + c];
    Q += part[(size_t)(98 + b) * DIMC + c];
  }
  float m = S * (1.0f / 6272.0f);
  float v = Q * (1.0f / 6272.0f) - m * m;
  v = fmaxf(v, 0.f);
  float rs = rsqrtf(v + 1e-5f);
  float sc = gam[c] * rs;
  scale[c] = sc;
  shift[c] = bet[c] - m * sc;
}

// ---------------- fused FFT-conv + ISTA per (b,g) tile ----------------
// Unnormalized fwd DFT, 1/196 inverse (ortho norms cancel in fft_conv).
// kk is rank-1 per freq: conv_f[i] = k_i * z, z = sum_j conj(k_j) sf_j.
// Recon z is Hermitian-projected on freq cols f=0,7 (irfft->rfft roundtrip),
// then multiplied by k2, then irfft2.
__global__ __launch_bounds__(64) void ista_k(
    const float* __restrict__ vxt, const float* __restrict__ kern,
    const float* __restrict__ kern2, const float* __restrict__ Lbuf,
    float* __restrict__ outp) {
  const int bid = blockIdx.x;
  const int g = bid >> 5, b = bid & 31;
  const int t = threadIdx.x;

  __shared__ float TC[196], TSn[196];
  __shared__ float xs[196];
  __shared__ float t1R[112], t1I[112];
  __shared__ float t2R[112], t2I[112];
  __shared__ float zr[112], zi[112];     // XF in fast phase, z in slow phase
  __shared__ float kR[5][112], kI[5][112];
  __shared__ float uu[5][196];
  __shared__ float ss[5][196];
  __shared__ float k2R[112], k2I[112];

  for (int i = t; i < 196; i += 64) {
    int a = i / 14, c = i - (i / 14) * 14;
    int m = (a * c) % 14;
    TC[i] = C14d[m]; TSn[i] = S14d[m];
  }
  for (int i = t; i < 560; i += 64) {
    int ii = i / 112, p = i - ii * 112;
    const float* kp = kern + ((size_t)g * 5 + ii) * 224 + p * 2;
    kR[ii][p] = kp[0]; kI[ii][p] = kp[1];
  }
  for (int i = t; i < 196; i += 64) xs[i] = vxt[((size_t)b * DIMC + g) * 196 + i];
  __syncthreads();

  // ---- DFT helpers (whole-wave, internal sync) ----
  auto rowsFwd = [&](const float* xsrc) {           // real rows -> t1 (112)
    for (int i = t; i < 112; i += 64) {
      int r = i >> 3, f = i & 7;
      const float* xp = xsrc + r * 14;
      const float* tc = &TC[f * 14]; const float* tsn = &TSn[f * 14];
      float ar = 0.f, ai = 0.f;
#pragma unroll
      for (int c = 0; c < 14; ++c) { float xv = xp[c]; ar += xv * tc[c]; ai -= xv * tsn[c]; }
      t1R[i] = ar; t1I[i] = ai;
    }
    __syncthreads();
  };
  auto colsFwd = [&](float* oR, float* oI) {        // t1 -> o, e^{-i}
    for (int i = t; i < 112; i += 64) {
      int kr = i >> 3, f = i & 7;
      const float* tc = &TC[kr * 14]; const float* tsn = &TSn[kr * 14];
      float br = 0.f, bi = 0.f;
#pragma unroll
      for (int r = 0; r < 14; ++r) {
        float xr = t1R[r * 8 + f], xi = t1I[r * 8 + f];
        br += tc[r] * xr + tsn[r] * xi;
        bi += tc[r] * xi - tsn[r] * xr;
      }
      oR[i] = br; oI[i] = bi;
    }
    __syncthreads();
  };
  auto colsInv = [&]() {                            // t1 -> t2, e^{+i}
    for (int i = t; i < 112; i += 64) {
      int r = i >> 3, f = i & 7;
      const float* tc = &TC[r * 14]; const float* tsn = &TSn[r * 14];
      float br = 0.f, bi = 0.f;
#pragma unroll
      for (int kr = 0; kr < 14; ++kr) {
        float xr = t1R[kr * 8 + f], xi = t1I[kr * 8 + f];
        br += tc[kr] * xr - tsn[kr] * xi;
        bi += tc[kr] * xi + tsn[kr] * xr;
      }
      t2R[i] = br; t2I[i] = bi;
    }
    __syncthreads();
  };
  auto rowVal = [&](int r, int c) -> float {        // numpy irfft last axis, incl 1/196
    const float* pR = &t2R[r * 8]; const float* pI = &t2I[r * 8];
    float v = pR[0] + ((c & 1) ? -pR[7] : pR[7]);
    float s2 = 0.f;
#pragma unroll
    for (int f = 1; f < 7; ++f) s2 += pR[f] * TC[f * 14 + c] - pI[f] * TSn[f * 14 + c];
    return (v + 2.f * s2) * (1.0f / 196.0f);
  };

  // ---- u_i = irfft2(K_i * rfft2(vx)) ----
  rowsFwd(xs);
  colsFwd(zr, zi);   // XF
  float am = 0.f;
  for (int ii = 0; ii < 5; ++ii) {
    for (int i = t; i < 112; i += 64) {
      float a = kR[ii][i], b2 = kI[ii][i];
      t1R[i] = a * zr[i] - b2 * zi[i];
      t1I[i] = a * zi[i] + b2 * zr[i];
    }
    __syncthreads();
    colsInv();
    for (int i = t; i < 196; i += 64) {
      float v = rowVal(i / 14, i - (i / 14) * 14);
      uu[ii][i] = v;
      am = fmaxf(am, fabsf(v));
    }
    __syncthreads();
  }
#pragma unroll
  for (int off = 32; off; off >>= 1) am = fmaxf(am, __shfl_xor(am, off));

  // exact early exit: |u| <= LAM everywhere  =>  s stays 0, new = 0
  if (am <= LAMC) {
    for (int i = t; i < 196; i += 64) outp[((size_t)(b * 196 + i)) * DIMC + g] = 0.f;
    return;
  }

  // ---- full ISTA ----
  const float invL = 1.0f / Lbuf[g];
  const float thr = LAMC * invL;
  {
    float* up = &uu[0][0];
    float* sp = &ss[0][0];
    for (int i = t; i < 980; i += 64) {
      float v = up[i];
      float a = fabsf(v) - LAMC;
      sp[i] = a > 0.f ? copysignf(a, v) : 0.f;
    }
  }
  for (int i = t; i < 112; i += 64) {
    k2R[i] = kern2[(size_t)g * 224 + i * 2];
    k2I[i] = kern2[(size_t)g * 224 + i * 2 + 1];
  }
  __syncthreads();

  for (int iter = 0; iter < 4; ++iter) {
    for (int i = t; i < 112; i += 64) { zr[i] = 0.f; zi[i] = 0.f; }
    __syncthreads();
    for (int ii = 0; ii < 5; ++ii) {
      rowsFwd(&ss[ii][0]);
      colsFwd(t2R, t2I);                 // SF_i
      for (int i = t; i < 112; i += 64) {
        float a = kR[ii][i], b2 = kI[ii][i];
        zr[i] += a * t2R[i] + b2 * t2I[i];   // conj(K_i)*SF_i
        zi[i] += a * t2I[i] - b2 * t2R[i];
      }
      __syncthreads();
    }
    if (iter == 3) break;                // last pass: z only (reconstruction)
    for (int ii = 0; ii < 5; ++ii) {
      for (int i = t; i < 112; i += 64) {
        float a = kR[ii][i], b2 = kI[ii][i];
        t1R[i] = a * zr[i] - b2 * zi[i];     // K_i * z
        t1I[i] = a * zi[i] + b2 * zr[i];
      }
      __syncthreads();
      colsInv();
      for (int i = t; i < 196; i += 64) {
        float v = rowVal(i / 14, i - (i / 14) * 14);      // conv_i
        float sv = ss[ii][i] - (v - uu[ii][i]) * invL;
        float aa = fabsf(sv) - thr;
        ss[ii][i] = aa > 0.f ? copysignf(aa, sv) : 0.f;
      }
      __syncthreads();
    }
  }

  // Hermitian projection of z on freq cols f=0 and f=7 (irfft->rfft roundtrip)
  if (t < 28) {
    int kr = t >> 1, f = (t & 1) * 7;
    int d = kr * 8 + f;
    int srci = ((14 - kr) % 14) * 8 + f;
    float pr = 0.5f * (zr[d] + zr[srci]);
    float pi = 0.5f * (zi[d] - zi[srci]);
    zr[d] = pr; zi[d] = pi;
  }
  __syncthreads();

  // new = irfft2(k2 * z')
  for (int i = t; i < 112; i += 64) {
    float a = k2R[i], b2 = k2I[i];
    t1R[i] = a * zr[i] - b2 * zi[i];
    t1I[i] = a * zi[i] + b2 * zr[i];
  }
  __syncthreads();
  colsInv();
  for (int i = t; i < 196; i += 64) {
    outp[((size_t)(b * 196 + i)) * DIMC + g] = rowVal(i / 14, i - (i / 14) * 14);
  }
}

// ---------------- launch ----------------
extern "C" void kernel_launch(void* const* d_in, const int* in_sizes, int n_in,
                              void* d_out, int out_size, void* d_ws, size_t ws_size,
                              hipStream_t stream) {
  (void)in_sizes; (void)n_in; (void)out_size;
  const float* x      = (const float*)d_in[0];
  const float* v_w    = (const float*)d_in[1];
  const float* proj_w = (const float*)d_in[2];
  const float* proj_b = (const float*)d_in[3];
  const float* kern   = (const float*)d_in[4];
  const float* kern2  = (const float*)d_in[5];
  const float* n1g    = (const float*)d_in[6];
  const float* n1b    = (const float*)d_in[7];
  const float* n2g    = (const float*)d_in[8];
  const float* n2b    = (const float*)d_in[9];
  const float* fc1w   = (const float*)d_in[10];
  const float* fc1b   = (const float*)d_in[11];
  const float* fc2w   = (const float*)d_in[12];
  const float* fc2b   = (const float*)d_in[13];
  const float* Lb     = (const float*)d_in[14];
  float* out = (float*)d_out;

  char* ws = (char*)d_ws;
  size_t o = 0;
  auto alloc = [&](size_t bytes) { size_t r = o; o += (bytes + 255) & ~(size_t)255; return r; };
  u16*   vwbf   = (u16*)(ws + alloc(589824 * 2));
  u16*   projbf = (u16*)(ws + alloc(589824 * 2));
  u16*   fc1bf  = (u16*)(ws + alloc(2359296 * 2));
  u16*   fc2bf  = (u16*)(ws + alloc(2359296 * 2));
  float* sc1    = (float*)(ws + alloc(768 * 4));
  float* sh1    = (float*)(ws + alloc(768 * 4));
  float* sc2    = (float*)(ws + alloc(768 * 4));
  float* sh2    = (float*)(ws + alloc(768 * 4));
  float* part   = (float*)(ws + alloc(98 * 768 * 2 * 4));
  float* vxt    = (float*)(ws + alloc((size_t)MTOT * DIMC * 4));   // 19267584 B
  float* newm   = (float*)(ws + alloc((size_t)MTOT * DIMC * 4));
  float* new2   = (float*)(ws + alloc((size_t)MTOT * DIMC * 4));
  u16*   hbf    = (u16*)vxt;   // overlay: h (6272x3072 bf16 = 38.5MB) over vxt+newm (both dead)
  if (ws_size < o) return;     // insufficient scratch; bail instead of corrupting

  // weights -> bf16
  cvt_k<<<2304, 256, 0, stream>>>(v_w, vwbf, 589824);
  cvt_k<<<2304, 256, 0, stream>>>(proj_w, projbf, 589824);
  cvt_k<<<9216, 256, 0, stream>>>(fc1w, fc1bf, 2359296);
  cvt_k<<<9216, 256, 0, stream>>>(fc2w, fc2bf, 2359296);

  // vx = x @ v_w^T, written transposed as (b, g, n)
  gemm_k<0, 0><<<dim3(12, 98), 256, 0, stream>>>(x, vwbf, nullptr, nullptr, nullptr, nullptr,
                                                 vxt, DIMC, DIMC);
  // fused FFT-conv + ISTA + reconstruction + kernel2 conv -> new (m, g)
  ista_k<<<24576, 64, 0, stream>>>(vxt, kern, kern2, Lb, newm);
  // BN1 stats
  stats_part_k<<<98, 256, 0, stream>>>(newm, part);
  stats_fin_k<<<3, 256, 0, stream>>>(part, n1g, n1b, sc1, sh1);
  // new2 = x + BN1(new) @ proj_w^T + proj_b
  gemm_k<1, 1><<<dim3(12, 98), 256, 0, stream>>>(newm, projbf, sc1, sh1, proj_b, x,
                                                 new2, DIMC, DIMC);
  // BN2 stats
  stats_part_k<<<98, 256, 0, stream>>>(new2, part);
  stats_fin_k<<<3, 256, 0, stream>>>(part, n2g, n2b, sc2, sh2);
  // h = gelu(BN2(new2) @ fc1^T + fc1_b)  (bf16)
  gemm_k<1, 2><<<dim3(48, 98), 256, 0, stream>>>(new2, fc1bf, sc2, sh2, fc1b, nullptr,
                                                 hbf, HIDC, DIMC);
  // out = new2 + h @ fc2^T + fc2_b
  gemm_k<2, 1><<<dim3(12, 98), 256, 0, stream>>>(hbf, fc2bf, nullptr, nullptr, fc2b, new2,
                                                 out, DIMC, HIDC);
}

// Round 2
// 381.183 us; speedup vs baseline: 1.2930x; 1.2930x over previous
//
#include <hip/hip_runtime.h>
#include <cmath>

typedef unsigned short u16;
typedef __bf16 bf16x8 __attribute__((ext_vector_type(8)));
typedef float f32x4 __attribute__((ext_vector_type(4)));
typedef float float4v __attribute__((ext_vector_type(4)));
typedef u16 ushort4v __attribute__((ext_vector_type(4)));

#define DIMC 768
#define NP 196
#define MTOT 6272         // 32*196
#define HIDC 3072
#define LAMC 3.5f

__device__ const float C14d[14] = {
  1.0f, 0.9009688679024191f, 0.6234898018587336f, 0.22252093395631445f,
  -0.22252093395631445f, -0.6234898018587336f, -0.9009688679024191f, -1.0f,
  -0.9009688679024191f, -0.6234898018587336f, -0.22252093395631445f,
  0.22252093395631445f, 0.6234898018587336f, 0.9009688679024191f
};
__device__ const float S14d[14] = {
  0.0f, 0.43388373911755823f, 0.7818314824680298f, 0.9749279121818236f,
  0.9749279121818236f, 0.7818314824680298f, 0.43388373911755823f, 0.0f,
  -0.43388373911755823f, -0.7818314824680298f, -0.9749279121818236f,
  -0.9749279121818236f, -0.7818314824680298f, -0.43388373911755823f
};

__device__ __forceinline__ u16 f2bf(float f) {
  unsigned u = __builtin_bit_cast(unsigned, f);
  unsigned r = u + 0x7FFFu + ((u >> 16) & 1u);
  return (u16)(r >> 16);
}

typedef const __attribute__((address_space(1))) u16* gas_p;
typedef __attribute__((address_space(3))) u16* las_p;
__device__ __forceinline__ void gl16(const u16* g, u16* l) {
  __builtin_amdgcn_global_load_lds((gas_p)g, (las_p)l, 16, 0, 0);
}

// ---------------- f32 -> bf16 convert (x4 vectorized) ----------------
__global__ __launch_bounds__(256) void cvt4_k(const float* __restrict__ s,
                                              u16* __restrict__ d, int n4) {
  int idx = blockIdx.x * 256 + threadIdx.x;
  if (idx >= n4) return;
  int i4 = idx * 4;
  float4v v = *(const float4v*)(s + i4);
  ushort4v o;
#pragma unroll
  for (int j = 0; j < 4; ++j) o[j] = f2bf(v[j]);
  *(ushort4v*)(d + i4) = o;
}

// ---------------- BN-normalize + convert to bf16 ----------------
__global__ __launch_bounds__(256) void bncvt_k(const float* __restrict__ s,
    const float* __restrict__ sc, const float* __restrict__ sh,
    u16* __restrict__ d, int n4) {
  int idx = blockIdx.x * 256 + threadIdx.x;
  if (idx >= n4) return;
  int i4 = idx * 4;
  int c = i4 % DIMC;
  float4v v = *(const float4v*)(s + i4);
  float4v a = *(const float4v*)(sc + c);
  float4v b = *(const float4v*)(sh + c);
  v = v * a + b;
  ushort4v o;
#pragma unroll
  for (int j = 0; j < 4; ++j) o[j] = f2bf(v[j]);
  *(ushort4v*)(d + i4) = o;
}

// ---------------- 128x128 bf16 MFMA GEMM (m97 structure) ----------------
// C = epi(A(bf16, MxK) * B(bf16, NxK)^T)
// EPI 0: f32 transpose-write  vxt[(b*768+n)*196+np], m=b*196+np
// EPI 1: f32 C[m*Nr+n] = acc + bias[n] + res[m*Nr+n]
// EPI 2: bf16 C[m*Nr+n] = gelu_exact(acc + bias[n])
template<int EPI>
__global__ __launch_bounds__(256) void gemm_k(
    const u16* __restrict__ A, const u16* __restrict__ Bw,
    const float* __restrict__ bias, const float* __restrict__ res,
    void* __restrict__ Cp, int Nr, int Kr) {
  __shared__ __attribute__((aligned(16))) u16 As[128 * 32];
  __shared__ __attribute__((aligned(16))) u16 Bs[128 * 32];
  const int t = threadIdx.x;
  const int wid = t >> 6, lane = t & 63;
  const int bn = blockIdx.x * 128, bm = blockIdx.y * 128;
  const int wm = (wid >> 1) * 64, wn = (wid & 1) * 64;
  const int l15 = lane & 15, l4 = lane >> 4;
  const int srow = lane >> 2, scol = (lane & 3) * 8;

  f32x4 acc[4][4];
#pragma unroll
  for (int a = 0; a < 4; ++a)
#pragma unroll
    for (int b2 = 0; b2 < 4; ++b2) acc[a][b2] = (f32x4){0.f, 0.f, 0.f, 0.f};

  const u16* gA0 = A + (size_t)(bm + wid * 16 + srow) * Kr + scol;
  const u16* gB0 = Bw + (size_t)(bn + wid * 16 + srow) * Kr + scol;
  u16* lA = As + wid * 512;   // +lane*8 implicit (16B/lane)
  u16* lB = Bs + wid * 512;

  for (int k0 = 0; k0 < Kr; k0 += 32) {
    gl16(gA0 + k0, lA);
    gl16(gA0 + (size_t)64 * Kr + k0, lA + 2048);
    gl16(gB0 + k0, lB);
    gl16(gB0 + (size_t)64 * Kr + k0, lB + 2048);
    __syncthreads();

    bf16x8 af[4], bfv[4];
#pragma unroll
    for (int mb = 0; mb < 4; ++mb)
      af[mb] = *(const bf16x8*)&As[(wm + mb * 16 + l15) * 32 + l4 * 8];
#pragma unroll
    for (int nb = 0; nb < 4; ++nb)
      bfv[nb] = *(const bf16x8*)&Bs[(wn + nb * 16 + l15) * 32 + l4 * 8];
#pragma unroll
    for (int mb = 0; mb < 4; ++mb)
#pragma unroll
      for (int nb = 0; nb < 4; ++nb)
        acc[mb][nb] = __builtin_amdgcn_mfma_f32_16x16x32_bf16(af[mb], bfv[nb], acc[mb][nb], 0, 0, 0);
    __syncthreads();
  }

#pragma unroll
  for (int mb = 0; mb < 4; ++mb) {
#pragma unroll
    for (int nb = 0; nb < 4; ++nb) {
      int n = bn + wn + nb * 16 + l15;
#pragma unroll
      for (int r = 0; r < 4; ++r) {
        int m = bm + wm + mb * 16 + l4 * 4 + r;
        float v = acc[mb][nb][r];
        if (EPI == 0) {
          int bb = m / 196, np = m - bb * 196;
          ((float*)Cp)[((size_t)bb * DIMC + n) * 196 + np] = v;
        } else if (EPI == 1) {
          ((float*)Cp)[(size_t)m * Nr + n] = v + bias[n] + res[(size_t)m * Nr + n];
        } else {
          float vb = v + bias[n];
          float ge = 0.5f * vb * (1.f + erff(vb * 0.70710678118654752f));
          ((u16*)Cp)[(size_t)m * Nr + n] = f2bf(ge);
        }
      }
    }
  }
}

// ---------------- BN stats (deterministic 2-stage) ----------------
__global__ __launch_bounds__(256) void stats_part_k(const float* __restrict__ A,
                                                    float* __restrict__ part) {
  int blk = blockIdx.x, t = threadIdx.x;
  float s0a = 0, s0b = 0, s0c = 0, s1a = 0, s1b = 0, s1c = 0;
  const float* base = A + (size_t)blk * 64 * DIMC;
  for (int r = 0; r < 64; ++r) {
    const float* row = base + (size_t)r * DIMC;
    float v0 = row[t], v1 = row[t + 256], v2 = row[t + 512];
    s0a += v0; s1a += v0 * v0;
    s0b += v1; s1b += v1 * v1;
    s0c += v2; s1c += v2 * v2;
  }
  part[(size_t)blk * DIMC + t] = s0a;
  part[(size_t)blk * DIMC + t + 256] = s0b;
  part[(size_t)blk * DIMC + t + 512] = s0c;
  float* p2 = part + 98 * DIMC;
  p2[(size_t)blk * DIMC + t] = s1a;
  p2[(size_t)blk * DIMC + t + 256] = s1b;
  p2[(size_t)blk * DIMC + t + 512] = s1c;
}

__global__ __launch_bounds__(256) void stats_fin_k(const float* __restrict__ part,
    const float* __restrict__ gam, const float* __restrict__ bet,
    float* __restrict__ scale, float* __restrict__ shift) {
  int c = blockIdx.x * 256 + threadIdx.x;
  if (c >= DIMC) return;
  float S = 0.f, Q = 0.f;
  for (int b = 0; b < 98; ++b) {
    S += part[(size_t)b * DIMC + c];
    Q += part[(size_t)(98 + b) * DIMC + c];
  }
  float m = S * (1.0f / 6272.0f);
  float v = Q * (1.0f / 6272.0f) - m * m;
  v = fmaxf(v, 0.f);
  float rs = rsqrtf(v + 1e-5f);
  float sc = gam[c] * rs;
  scale[c] = sc;
  shift[c] = bet[c] - m * sc;
}

// ---------------- fast check: compute max|u|, flag stragglers ----------------
// 4 tiles per 256-thread block (1 tile/wave). XF kept in registers; K read
// from global (L2-resident); no output write (newm pre-zeroed by memset).
__global__ __launch_bounds__(256) void check_k(
    const float* __restrict__ vxt, const float* __restrict__ kern,
    int* __restrict__ cnt, int* __restrict__ wl) {
  __shared__ float TC[196], TSn[196];
  __shared__ float xs[4][196];
  __shared__ float t1R[4][112], t1I[4][112];
  __shared__ float t2R[4][112], t2I[4][112];
  const int t = threadIdx.x, w = t >> 6, lane = t & 63;
  const int tile = blockIdx.x * 4 + w;
  const int g = tile >> 5, b = tile & 31;

  for (int i = t; i < 196; i += 256) {
    int a = i / 14, c = i - (i / 14) * 14;
    int m = (a * c) % 14;
    TC[i] = C14d[m]; TSn[i] = S14d[m];
  }
  const float* xsrc = vxt + ((size_t)b * DIMC + g) * 196;
  for (int i = lane; i < 196; i += 64) xs[w][i] = xsrc[i];
  __syncthreads();

  // rows forward
  for (int i = lane; i < 112; i += 64) {
    int r = i >> 3, f = i & 7;
    const float* xp = &xs[w][r * 14];
    const float* tc = &TC[f * 14]; const float* ts = &TSn[f * 14];
    float ar = 0.f, ai = 0.f;
#pragma unroll
    for (int c = 0; c < 14; ++c) { float xv = xp[c]; ar += xv * tc[c]; ai -= xv * ts[c]; }
    t1R[w][i] = ar; t1I[w][i] = ai;
  }
  __syncthreads();

  // cols forward -> XF in registers (lane holds i=lane; lanes<48 also i=lane+64)
  float xfR[2], xfI[2];
#pragma unroll
  for (int jj = 0; jj < 2; ++jj) {
    int i = lane + jj * 64;
    if (jj == 0 || lane < 48) {
      int kr = i >> 3, f = i & 7;
      const float* tc = &TC[kr * 14]; const float* ts = &TSn[kr * 14];
      float br = 0.f, bi = 0.f;
#pragma unroll
      for (int r = 0; r < 14; ++r) {
        float xr = t1R[w][r * 8 + f], xi = t1I[w][r * 8 + f];
        br += tc[r] * xr + ts[r] * xi;
        bi += tc[r] * xi - ts[r] * xr;
      }
      xfR[jj] = br; xfI[jj] = bi;
    }
  }
  __syncthreads();

  float am = 0.f;
  for (int ii = 0; ii < 5; ++ii) {
    const float* kp = kern + ((size_t)g * 5 + ii) * 224;
#pragma unroll
    for (int jj = 0; jj < 2; ++jj) {
      int i = lane + jj * 64;
      if (jj == 0 || lane < 48) {
        float a = kp[i * 2], b2 = kp[i * 2 + 1];
        t1R[w][i] = a * xfR[jj] - b2 * xfI[jj];
        t1I[w][i] = a * xfI[jj] + b2 * xfR[jj];
      }
    }
    __syncthreads();
    for (int i = lane; i < 112; i += 64) {       // cols inverse
      int r = i >> 3, f = i & 7;
      const float* tc = &TC[r * 14]; const float* ts = &TSn[r * 14];
      float br = 0.f, bi = 0.f;
#pragma unroll
      for (int kr = 0; kr < 14; ++kr) {
        float xr = t1R[w][kr * 8 + f], xi = t1I[w][kr * 8 + f];
        br += tc[kr] * xr - ts[kr] * xi;
        bi += tc[kr] * xi + ts[kr] * xr;
      }
      t2R[w][i] = br; t2I[w][i] = bi;
    }
    __syncthreads();
    for (int i = lane; i < 196; i += 64) {       // rows inverse + max
      int r = i / 14, c = i - (i / 14) * 14;
      const float* pR = &t2R[w][r * 8]; const float* pI = &t2I[w][r * 8];
      float v = pR[0] + ((c & 1) ? -pR[7] : pR[7]);
      float s2 = 0.f;
#pragma unroll
      for (int f = 1; f < 7; ++f) s2 += pR[f] * TC[f * 14 + c] - pI[f] * TSn[f * 14 + c];
      am = fmaxf(am, fabsf(v + 2.f * s2));
    }
    __syncthreads();
  }
  am *= (1.0f / 196.0f);
#pragma unroll
  for (int off = 32; off; off >>= 1) am = fmaxf(am, __shfl_xor(am, off));
  if (lane == 0 && am > LAMC) {
    int idx = atomicAdd(cnt, 1);
    wl[idx] = tile;
  }
}

// ---------------- full ISTA for flagged tiles (round-1 verified path) ----------------
__global__ __launch_bounds__(64) void slow_k(
    const float* __restrict__ vxt, const float* __restrict__ kern,
    const float* __restrict__ kern2, const float* __restrict__ Lbuf,
    const int* __restrict__ cnt, const int* __restrict__ wl,
    float* __restrict__ outp) {
  const int t = threadIdx.x;
  __shared__ float TC[196], TSn[196];
  __shared__ float xs[196];
  __shared__ float t1R[112], t1I[112];
  __shared__ float t2R[112], t2I[112];
  __shared__ float zr[112], zi[112];
  __shared__ float kR[5][112], kI[5][112];
  __shared__ float uu[5][196];
  __shared__ float ss[5][196];
  __shared__ float k2R[112], k2I[112];

  for (int i = t; i < 196; i += 64) {
    int a = i / 14, c = i - (i / 14) * 14;
    int m = (a * c) % 14;
    TC[i] = C14d[m]; TSn[i] = S14d[m];
  }
  const int ntile = *cnt;

  auto rowsFwd = [&](const float* xsrc) {
    for (int i = t; i < 112; i += 64) {
      int r = i >> 3, f = i & 7;
      const float* xp = xsrc + r * 14;
      const float* tc = &TC[f * 14]; const float* tsn = &TSn[f * 14];
      float ar = 0.f, ai = 0.f;
#pragma unroll
      for (int c = 0; c < 14; ++c) { float xv = xp[c]; ar += xv * tc[c]; ai -= xv * tsn[c]; }
      t1R[i] = ar; t1I[i] = ai;
    }
    __syncthreads();
  };
  auto colsFwd = [&](float* oR, float* oI) {
    for (int i = t; i < 112; i += 64) {
      int kr = i >> 3, f = i & 7;
      const float* tc = &TC[kr * 14]; const float* tsn = &TSn[kr * 14];
      float br = 0.f, bi = 0.f;
#pragma unroll
      for (int r = 0; r < 14; ++r) {
        float xr = t1R[r * 8 + f], xi = t1I[r * 8 + f];
        br += tc[r] * xr + tsn[r] * xi;
        bi += tc[r] * xi - tsn[r] * xr;
      }
      oR[i] = br; oI[i] = bi;
    }
    __syncthreads();
  };
  auto colsInv = [&]() {
    for (int i = t; i < 112; i += 64) {
      int r = i >> 3, f = i & 7;
      const float* tc = &TC[r * 14]; const float* tsn = &TSn[r * 14];
      float br = 0.f, bi = 0.f;
#pragma unroll
      for (int kr = 0; kr < 14; ++kr) {
        float xr = t1R[kr * 8 + f], xi = t1I[kr * 8 + f];
        br += tc[kr] * xr - tsn[kr] * xi;
        bi += tc[kr] * xi + tsn[kr] * xr;
      }
      t2R[i] = br; t2I[i] = bi;
    }
    __syncthreads();
  };
  auto rowVal = [&](int r, int c) -> float {
    const float* pR = &t2R[r * 8]; const float* pI = &t2I[r * 8];
    float v = pR[0] + ((c & 1) ? -pR[7] : pR[7]);
    float s2 = 0.f;
#pragma unroll
    for (int f = 1; f < 7; ++f) s2 += pR[f] * TC[f * 14 + c] - pI[f] * TSn[f * 14 + c];
    return (v + 2.f * s2) * (1.0f / 196.0f);
  };

  for (int widx = blockIdx.x; widx < ntile; widx += gridDim.x) {
    const int tile = wl[widx];
    const int g = tile >> 5, b = tile & 31;
    __syncthreads();
    for (int i = t; i < 560; i += 64) {
      int ii = i / 112, p = i - ii * 112;
      const float* kp = kern + ((size_t)g * 5 + ii) * 224 + p * 2;
      kR[ii][p] = kp[0]; kI[ii][p] = kp[1];
    }
    for (int i = t; i < 196; i += 64) xs[i] = vxt[((size_t)b * DIMC + g) * 196 + i];
    for (int i = t; i < 112; i += 64) {
      k2R[i] = kern2[(size_t)g * 224 + i * 2];
      k2I[i] = kern2[(size_t)g * 224 + i * 2 + 1];
    }
    __syncthreads();

    rowsFwd(xs);
    colsFwd(zr, zi);       // XF
    for (int ii = 0; ii < 5; ++ii) {
      for (int i = t; i < 112; i += 64) {
        float a = kR[ii][i], b2 = kI[ii][i];
        t1R[i] = a * zr[i] - b2 * zi[i];
        t1I[i] = a * zi[i] + b2 * zr[i];
      }
      __syncthreads();
      colsInv();
      for (int i = t; i < 196; i += 64) uu[ii][i] = rowVal(i / 14, i - (i / 14) * 14);
      __syncthreads();
    }

    const float invL = 1.0f / Lbuf[g];
    const float thr = LAMC * invL;
    {
      float* up = &uu[0][0];
      float* sp = &ss[0][0];
      for (int i = t; i < 980; i += 64) {
        float v = up[i];
        float a = fabsf(v) - LAMC;
        sp[i] = a > 0.f ? copysignf(a, v) : 0.f;
      }
    }
    __syncthreads();

    for (int iter = 0; iter < 4; ++iter) {
      for (int i = t; i < 112; i += 64) { zr[i] = 0.f; zi[i] = 0.f; }
      __syncthreads();
      for (int ii = 0; ii < 5; ++ii) {
        rowsFwd(&ss[ii][0]);
        colsFwd(t2R, t2I);
        for (int i = t; i < 112; i += 64) {
          float a = kR[ii][i], b2 = kI[ii][i];
          zr[i] += a * t2R[i] + b2 * t2I[i];
          zi[i] += a * t2I[i] - b2 * t2R[i];
        }
        __syncthreads();
      }
      if (iter == 3) break;
      for (int ii = 0; ii < 5; ++ii) {
        for (int i = t; i < 112; i += 64) {
          float a = kR[ii][i], b2 = kI[ii][i];
          t1R[i] = a * zr[i] - b2 * zi[i];
          t1I[i] = a * zi[i] + b2 * zr[i];
        }
        __syncthreads();
        colsInv();
        for (int i = t; i < 196; i += 64) {
          float v = rowVal(i / 14, i - (i / 14) * 14);
          float sv = ss[ii][i] - (v - uu[ii][i]) * invL;
          float aa = fabsf(sv) - thr;
          ss[ii][i] = aa > 0.f ? copysignf(aa, sv) : 0.f;
        }
        __syncthreads();
      }
    }

    if (t < 28) {     // Hermitian projection on freq cols f=0,7
      int kr = t >> 1, f = (t & 1) * 7;
      int d = kr * 8 + f;
      int srci = ((14 - kr) % 14) * 8 + f;
      float pr = 0.5f * (zr[d] + zr[srci]);
      float pi = 0.5f * (zi[d] - zi[srci]);
      zr[d] = pr; zi[d] = pi;
    }
    __syncthreads();
    for (int i = t; i < 112; i += 64) {
      float a = k2R[i], b2 = k2I[i];
      t1R[i] = a * zr[i] - b2 * zi[i];
      t1I[i] = a * zi[i] + b2 * zr[i];
    }
    __syncthreads();
    colsInv();
    for (int i = t; i < 196; i += 64)
      outp[((size_t)(b * 196 + i)) * DIMC + g] = rowVal(i / 14, i - (i / 14) * 14);
  }
}

// ---------------- launch ----------------
extern "C" void kernel_launch(void* const* d_in, const int* in_sizes, int n_in,
                              void* d_out, int out_size, void* d_ws, size_t ws_size,
                              hipStream_t stream) {
  (void)in_sizes; (void)n_in; (void)out_size;
  const float* x      = (const float*)d_in[0];
  const float* v_w    = (const float*)d_in[1];
  const float* proj_w = (const float*)d_in[2];
  const float* proj_b = (const float*)d_in[3];
  const float* kern   = (const float*)d_in[4];
  const float* kern2  = (const float*)d_in[5];
  const float* n1g    = (const float*)d_in[6];
  const float* n1b    = (const float*)d_in[7];
  const float* n2g    = (const float*)d_in[8];
  const float* n2b    = (const float*)d_in[9];
  const float* fc1w   = (const float*)d_in[10];
  const float* fc1b   = (const float*)d_in[11];
  const float* fc2w   = (const float*)d_in[12];
  const float* fc2b   = (const float*)d_in[13];
  const float* Lb     = (const float*)d_in[14];
  float* out = (float*)d_out;

  char* ws = (char*)d_ws;
  size_t o = 0;
  auto alloc = [&](size_t bytes) { size_t r = o; o += (bytes + 255) & ~(size_t)255; return r; };
  u16*   vwbf   = (u16*)(ws + alloc(589824 * 2));
  u16*   projbf = (u16*)(ws + alloc(589824 * 2));
  u16*   fc1bf  = (u16*)(ws + alloc(2359296 * 2));
  u16*   fc2bf  = (u16*)(ws + alloc(2359296 * 2));
  float* sc1    = (float*)(ws + alloc(768 * 4));
  float* sh1    = (float*)(ws + alloc(768 * 4));
  float* sc2    = (float*)(ws + alloc(768 * 4));
  float* sh2    = (float*)(ws + alloc(768 * 4));
  float* part   = (float*)(ws + alloc(98 * 768 * 2 * 4));
  int*   cnt    = (int*)(ws + alloc(4));
  int*   wl     = (int*)(ws + alloc(24576 * 4));
  u16*   abf    = (u16*)(ws + alloc((size_t)MTOT * DIMC * 2));   // xbf/newbf/new2bf (serial reuse)
  float* vxt    = (float*)(ws + alloc((size_t)MTOT * DIMC * 4)); // 19267584 B
  float* newm   = (float*)(ws + alloc((size_t)MTOT * DIMC * 4));
  float* new2   = (float*)(ws + alloc((size_t)MTOT * DIMC * 4));
  u16*   hbf    = (u16*)vxt;   // overlay: h (6272x3072 bf16 = 38535168 B) over vxt+newm (dead)
  if (ws_size < o) return;

  hipMemsetAsync(newm, 0, (size_t)MTOT * DIMC * 4, stream);
  hipMemsetAsync(cnt, 0, 4, stream);

  // weights + x -> bf16
  cvt4_k<<<576, 256, 0, stream>>>(v_w, vwbf, 147456);
  cvt4_k<<<576, 256, 0, stream>>>(proj_w, projbf, 147456);
  cvt4_k<<<2304, 256, 0, stream>>>(fc1w, fc1bf, 589824);
  cvt4_k<<<2304, 256, 0, stream>>>(fc2w, fc2bf, 589824);
  cvt4_k<<<4704, 256, 0, stream>>>(x, abf, 1204224);

  // vx = x @ v_w^T, transpose-written as (b, g, n)
  gemm_k<0><<<dim3(6, 49), 256, 0, stream>>>(abf, vwbf, nullptr, nullptr, vxt, DIMC, DIMC);
  // fast max|u| check -> worklist (newm stays zero for clean tiles)
  check_k<<<6144, 256, 0, stream>>>(vxt, kern, cnt, wl);
  // full ISTA only for flagged tiles
  slow_k<<<1024, 64, 0, stream>>>(vxt, kern, kern2, Lb, cnt, wl, newm);
  // BN1
  stats_part_k<<<98, 256, 0, stream>>>(newm, part);
  stats_fin_k<<<3, 256, 0, stream>>>(part, n1g, n1b, sc1, sh1);
  bncvt_k<<<4704, 256, 0, stream>>>(newm, sc1, sh1, abf, 1204224);
  // new2 = x + BN1(new) @ proj_w^T + proj_b
  gemm_k<1><<<dim3(6, 49), 256, 0, stream>>>(abf, projbf, proj_b, x, new2, DIMC, DIMC);
  // BN2
  stats_part_k<<<98, 256, 0, stream>>>(new2, part);
  stats_fin_k<<<3, 256, 0, stream>>>(part, n2g, n2b, sc2, sh2);
  bncvt_k<<<4704, 256, 0, stream>>>(new2, sc2, sh2, abf, 1204224);
  // h = gelu(BN2(new2) @ fc1^T + fc1_b)
  gemm_k<2><<<dim3(24, 49), 256, 0, stream>>>(abf, fc1bf, fc1b, nullptr, hbf, HIDC, DIMC);
  // out = new2 + h @ fc2^T + fc2_b
  gemm_k<1><<<dim3(6, 49), 256, 0, stream>>>(hbf, fc2bf, fc2b, new2, out, DIMC, HIDC);
}

// Round 3
// 333.765 us; speedup vs baseline: 1.4767x; 1.1421x over previous
//
#include <hip/hip_runtime.h>
#include <cmath>

typedef unsigned short u16;
typedef __bf16 bf16x8 __attribute__((ext_vector_type(8)));
typedef float f32x4 __attribute__((ext_vector_type(4)));
typedef float float4v __attribute__((ext_vector_type(4)));
typedef u16 ushort4v __attribute__((ext_vector_type(4)));
typedef u16 ushort8v __attribute__((ext_vector_type(8)));

#define DIMC 768
#define NP 196
#define MTOT 6272         // 32*196
#define HIDC 3072
#define LAMC 3.5f

__device__ const float C14d[14] = {
  1.0f, 0.9009688679024191f, 0.6234898018587336f, 0.22252093395631445f,
  -0.22252093395631445f, -0.6234898018587336f, -0.9009688679024191f, -1.0f,
  -0.9009688679024191f, -0.6234898018587336f, -0.22252093395631445f,
  0.22252093395631445f, 0.6234898018587336f, 0.9009688679024191f
};
__device__ const float S14d[14] = {
  0.0f, 0.43388373911755823f, 0.7818314824680298f, 0.9749279121818236f,
  0.9749279121818236f, 0.7818314824680298f, 0.43388373911755823f, 0.0f,
  -0.43388373911755823f, -0.7818314824680298f, -0.9749279121818236f,
  -0.9749279121818236f, -0.7818314824680298f, -0.43388373911755823f
};

__device__ __forceinline__ u16 f2bf(float f) {
  unsigned u = __builtin_bit_cast(unsigned, f);
  unsigned r = u + 0x7FFFu + ((u >> 16) & 1u);
  return (u16)(r >> 16);
}

typedef const __attribute__((address_space(1))) u16* gas_p;
typedef __attribute__((address_space(3))) u16* las_p;
__device__ __forceinline__ void gl16(const u16* g, u16* l) {
  __builtin_amdgcn_global_load_lds((gas_p)g, (las_p)l, 16, 0, 0);
}

// ---------------- build fragment-ordered DFT matrices F (224x224) / G (208x224) ----
// F[s][q]: s=2*(kr*8+f)+ri, q=r*14+c (q>=196 -> 0). val = ri? -sin : cos of 2pi(kr*r+f*c)/14
// G[p][s]: u[p] = sum_s G[p][s]*y[s]; val = (w_f/196)*(ri? -sin : cos), w_{0,7}=1 else 2
__global__ __launch_bounds__(256) void initfg_k(u16* __restrict__ Ff, u16* __restrict__ Gf) {
  int idx = blockIdx.x * 256 + threadIdx.x;
  if (idx < 50176) {                       // Ff: 14*7*64*8
    int j = idx & 7, lane = (idx >> 3) & 63;
    int mk = idx >> 9, k0 = mk % 7, m0 = mk / 7;
    int s = m0 * 16 + (lane & 15);
    int q = k0 * 32 + (lane >> 4) * 8 + j;
    float v = 0.f;
    if (q < 196) {
      int kr = s >> 4, f = (s >> 1) & 7, r = q / 14, c = q % 14;
      int th = (kr * r + f * c) % 14;
      v = (s & 1) ? -S14d[th] : C14d[th];
    }
    Ff[idx] = f2bf(v);
  } else if (idx < 50176 + 46592) {        // Gf: 13*7*64*8
    int t = idx - 50176;
    int j = t & 7, lane = (t >> 3) & 63;
    int pk = t >> 9, k0 = pk % 7, p0 = pk / 7;
    int p = p0 * 16 + (lane & 15);
    int s = k0 * 32 + (lane >> 4) * 8 + j;
    float v = 0.f;
    if (p < 196) {
      int kr = s >> 4, f = (s >> 1) & 7, r = p / 14, c = p % 14;
      int th = (kr * r + f * c) % 14;
      float w = (f == 0 || f == 7) ? 1.f : 2.f;
      v = (w * (1.f / 196.f)) * ((s & 1) ? -S14d[th] : C14d[th]);
    }
    Gf[t] = f2bf(v);
  }
}

// ---------------- fused weight convert (4 arrays, one dispatch) ----------------
__global__ __launch_bounds__(256) void cvtw_k(
    const float* __restrict__ w0, const float* __restrict__ w1,
    const float* __restrict__ w2, const float* __restrict__ w3,
    u16* __restrict__ o0, u16* __restrict__ o1,
    u16* __restrict__ o2, u16* __restrict__ o3) {
  int idx = blockIdx.x * 256 + threadIdx.x;
  const float* s; u16* d; int base;
  if (idx < 147456)      { s = w0; d = o0; base = 0; }
  else if (idx < 294912) { s = w1; d = o1; base = 147456; }
  else if (idx < 884736) { s = w2; d = o2; base = 294912; }
  else                   { s = w3; d = o3; base = 884736; }
  int i4 = (idx - base) * 4;
  float4v v = *(const float4v*)(s + i4);
  ushort4v o;
#pragma unroll
  for (int j = 0; j < 4; ++j) o[j] = f2bf(v[j]);
  *(ushort4v*)(d + i4) = o;
}

__global__ __launch_bounds__(256) void cvt4_k(const float* __restrict__ s,
                                              u16* __restrict__ d, int n4) {
  int idx = blockIdx.x * 256 + threadIdx.x;
  if (idx >= n4) return;
  int i4 = idx * 4;
  float4v v = *(const float4v*)(s + i4);
  ushort4v o;
#pragma unroll
  for (int j = 0; j < 4; ++j) o[j] = f2bf(v[j]);
  *(ushort4v*)(d + i4) = o;
}

// ---------------- BN-normalize + convert to bf16 ----------------
__global__ __launch_bounds__(256) void bncvt_k(const float* __restrict__ s,
    const float* __restrict__ sc, const float* __restrict__ sh,
    u16* __restrict__ d, int n4) {
  int idx = blockIdx.x * 256 + threadIdx.x;
  if (idx >= n4) return;
  int i4 = idx * 4;
  int c = i4 % DIMC;
  float4v v = *(const float4v*)(s + i4);
  float4v a = *(const float4v*)(sc + c);
  float4v b = *(const float4v*)(sh + c);
  v = v * a + b;
  ushort4v o;
#pragma unroll
  for (int j = 0; j < 4; ++j) o[j] = f2bf(v[j]);
  *(ushort4v*)(d + i4) = o;
}

// ---------------- 128x128 bf16 MFMA GEMM (m97 structure) ----------------
template<int EPI>
__global__ __launch_bounds__(256) void gemm_k(
    const u16* __restrict__ A, const u16* __restrict__ Bw,
    const float* __restrict__ bias, const float* __restrict__ res,
    void* __restrict__ Cp, int Nr, int Kr) {
  __shared__ __attribute__((aligned(16))) u16 As[128 * 32];
  __shared__ __attribute__((aligned(16))) u16 Bs[128 * 32];
  const int t = threadIdx.x;
  const int wid = t >> 6, lane = t & 63;
  const int bn = blockIdx.x * 128, bm = blockIdx.y * 128;
  const int wm = (wid >> 1) * 64, wn = (wid & 1) * 64;
  const int l15 = lane & 15, l4 = lane >> 4;
  const int srow = lane >> 2, scol = (lane & 3) * 8;

  f32x4 acc[4][4];
#pragma unroll
  for (int a = 0; a < 4; ++a)
#pragma unroll
    for (int b2 = 0; b2 < 4; ++b2) acc[a][b2] = (f32x4){0.f, 0.f, 0.f, 0.f};

  const u16* gA0 = A + (size_t)(bm + wid * 16 + srow) * Kr + scol;
  const u16* gB0 = Bw + (size_t)(bn + wid * 16 + srow) * Kr + scol;
  u16* lA = As + wid * 512;
  u16* lB = Bs + wid * 512;

  for (int k0 = 0; k0 < Kr; k0 += 32) {
    gl16(gA0 + k0, lA);
    gl16(gA0 + (size_t)64 * Kr + k0, lA + 2048);
    gl16(gB0 + k0, lB);
    gl16(gB0 + (size_t)64 * Kr + k0, lB + 2048);
    __syncthreads();

    bf16x8 af[4], bfv[4];
#pragma unroll
    for (int mb = 0; mb < 4; ++mb)
      af[mb] = *(const bf16x8*)&As[(wm + mb * 16 + l15) * 32 + l4 * 8];
#pragma unroll
    for (int nb = 0; nb < 4; ++nb)
      bfv[nb] = *(const bf16x8*)&Bs[(wn + nb * 16 + l15) * 32 + l4 * 8];
#pragma unroll
    for (int mb = 0; mb < 4; ++mb)
#pragma unroll
      for (int nb = 0; nb < 4; ++nb)
        acc[mb][nb] = __builtin_amdgcn_mfma_f32_16x16x32_bf16(af[mb], bfv[nb], acc[mb][nb], 0, 0, 0);
    __syncthreads();
  }

#pragma unroll
  for (int mb = 0; mb < 4; ++mb) {
#pragma unroll
    for (int nb = 0; nb < 4; ++nb) {
      int n = bn + wn + nb * 16 + l15;
#pragma unroll
      for (int r = 0; r < 4; ++r) {
        int m = bm + wm + mb * 16 + l4 * 4 + r;
        float v = acc[mb][nb][r];
        if (EPI == 0) {
          int bb = m / 196, np = m - bb * 196;
          ((float*)Cp)[((size_t)bb * DIMC + n) * 196 + np] = v;
        } else if (EPI == 1) {
          ((float*)Cp)[(size_t)m * Nr + n] = v + bias[n] + res[(size_t)m * Nr + n];
        } else {
          float vb = v + bias[n];
          float ge = 0.5f * vb * (1.f + erff(vb * 0.70710678118654752f));
          ((u16*)Cp)[(size_t)m * Nr + n] = f2bf(ge);
        }
      }
    }
  }
}

// ---------------- BN stats (deterministic 2-stage) ----------------
__global__ __launch_bounds__(256) void stats_part_k(const float* __restrict__ A,
                                                    float* __restrict__ part) {
  int blk = blockIdx.x, t = threadIdx.x;
  float s0a = 0, s0b = 0, s0c = 0, s1a = 0, s1b = 0, s1c = 0;
  const float* base = A + (size_t)blk * 64 * DIMC;
  for (int r = 0; r < 64; ++r) {
    const float* row = base + (size_t)r * DIMC;
    float v0 = row[t], v1 = row[t + 256], v2 = row[t + 512];
    s0a += v0; s1a += v0 * v0;
    s0b += v1; s1b += v1 * v1;
    s0c += v2; s1c += v2 * v2;
  }
  part[(size_t)blk * DIMC + t] = s0a;
  part[(size_t)blk * DIMC + t + 256] = s0b;
  part[(size_t)blk * DIMC + t + 512] = s0c;
  float* p2 = part + 98 * DIMC;
  p2[(size_t)blk * DIMC + t] = s1a;
  p2[(size_t)blk * DIMC + t + 256] = s1b;
  p2[(size_t)blk * DIMC + t + 512] = s1c;
}

__global__ __launch_bounds__(256) void stats_fin_k(const float* __restrict__ part,
    const float* __restrict__ gam, const float* __restrict__ bet,
    float* __restrict__ scale, float* __restrict__ shift) {
  int c = blockIdx.x * 256 + threadIdx.x;
  if (c >= DIMC) return;
  float S = 0.f, Q = 0.f;
  for (int b = 0; b < 98; ++b) {
    S += part[(size_t)b * DIMC + c];
    Q += part[(size_t)(98 + b) * DIMC + c];
  }
  float m = S * (1.0f / 6272.0f);
  float v = Q * (1.0f / 6272.0f) - m * m;
  v = fmaxf(v, 0.f);
  float rs = rsqrtf(v + 1e-5f);
  float sc = gam[c] * rs;
  scale[c] = sc;
  shift[c] = bet[c] - m * sc;
}

// ---------------- MFMA screen: max_i max_p |u_i| per tile, flag > 3.4 ----------
// One wave per 16-tile batch (same g, b = bhalf*16 + lane&15).
// XF(224 x 16tiles) = F*x via 98 MFMA; y_i = K_i o XF (VALU, via LDS transposer);
// u_i(208 x 16) = G*y_i via 455 MFMA. Flag -> exact fp32 slow path (over-flag safe).
__global__ __launch_bounds__(64) void checkmfma_k(
    const float* __restrict__ vxt, const float* __restrict__ kern,
    const u16* __restrict__ Ff, const u16* __restrict__ Gf,
    int* __restrict__ cnt, int* __restrict__ wl) {
  __shared__ float xf[16 * 228];          // [tile][s], stride 228 (2-way bank)
  const int lane = threadIdx.x;
  const int wgb = blockIdx.x;             // 0..1535
  const int g = wgb >> 1, bhalf = wgb & 1;
  const int tl = lane & 15, h = lane >> 4;
  const float* xbase = vxt + ((size_t)(bhalf * 16 + tl) * DIMC + g) * 196;

  // B-frags of x (bf16), k = q = k0*32 + h*8 + j, zero-pad q>=196
  bf16x8 Bx[7];
#pragma unroll
  for (int k0 = 0; k0 < 7; ++k0) {
    int q0 = k0 * 32 + h * 8;
    ushort8v tv;
    if (k0 < 6) {
      float4v f0 = *(const float4v*)(xbase + q0);
      float4v f1 = *(const float4v*)(xbase + q0 + 4);
#pragma unroll
      for (int j = 0; j < 4; ++j) { tv[j] = f2bf(f0[j]); tv[j + 4] = f2bf(f1[j]); }
    } else {
#pragma unroll
      for (int j = 0; j < 8; ++j) {
        int q = q0 + j;
        tv[j] = (q < 196) ? f2bf(xbase[q]) : (u16)0;
      }
    }
    Bx[k0] = __builtin_bit_cast(bf16x8, tv);
  }

  // XF = F * x  (D: col=tile, rows = s = m0*16 + h*4 + r) -> LDS
  for (int m0 = 0; m0 < 14; ++m0) {
    f32x4 acc = (f32x4){0.f, 0.f, 0.f, 0.f};
#pragma unroll
    for (int k0 = 0; k0 < 7; ++k0) {
      bf16x8 Af = __builtin_bit_cast(bf16x8,
          *(const ushort8v*)(Ff + ((size_t)(m0 * 7 + k0) * 64 + lane) * 8));
      acc = __builtin_amdgcn_mfma_f32_16x16x32_bf16(Af, Bx[k0], acc, 0, 0, 0);
    }
    *(f32x4*)&xf[tl * 228 + m0 * 16 + h * 4] = acc;
  }

  // y_i = K_i o XF, packed directly into B-frag layout (col=tile, k=s)
  bf16x8 By[5][7];
#pragma unroll
  for (int i = 0; i < 5; ++i) {
    const float* kb = kern + ((size_t)g * 5 + i) * 224;
#pragma unroll
    for (int k0 = 0; k0 < 7; ++k0) {
      f32x4 x0 = *(const f32x4*)&xf[tl * 228 + k0 * 32 + h * 8];
      f32x4 x1 = *(const f32x4*)&xf[tl * 228 + k0 * 32 + h * 8 + 4];
      int mb = k0 * 16 + h * 4;
      float2 ka = *(const float2*)(kb + (mb + 0) * 2);
      float2 kc = *(const float2*)(kb + (mb + 1) * 2);
      float2 ke = *(const float2*)(kb + (mb + 2) * 2);
      float2 kg = *(const float2*)(kb + (mb + 3) * 2);
      ushort8v tv;
      tv[0] = f2bf(ka.x * x0[0] - ka.y * x0[1]);
      tv[1] = f2bf(ka.x * x0[1] + ka.y * x0[0]);
      tv[2] = f2bf(kc.x * x0[2] - kc.y * x0[3]);
      tv[3] = f2bf(kc.x * x0[3] + kc.y * x0[2]);
      tv[4] = f2bf(ke.x * x1[0] - ke.y * x1[1]);
      tv[5] = f2bf(ke.x * x1[1] + ke.y * x1[0]);
      tv[6] = f2bf(kg.x * x1[0 + 2] - kg.y * x1[3]);
      tv[7] = f2bf(kg.x * x1[3] + kg.y * x1[2]);
      By[i][k0] = __builtin_bit_cast(bf16x8, tv);
    }
  }

  // u_i = G * y_i ; running max per lane (lane's tile = tl)
  float vmax = 0.f;
  for (int p0 = 0; p0 < 13; ++p0) {
    f32x4 a0 = (f32x4){0.f, 0.f, 0.f, 0.f};
    f32x4 a1 = a0, a2 = a0, a3 = a0, a4 = a0;
#pragma unroll
    for (int k0 = 0; k0 < 7; ++k0) {
      bf16x8 Ag = __builtin_bit_cast(bf16x8,
          *(const ushort8v*)(Gf + ((size_t)(p0 * 7 + k0) * 64 + lane) * 8));
      a0 = __builtin_amdgcn_mfma_f32_16x16x32_bf16(Ag, By[0][k0], a0, 0, 0, 0);
      a1 = __builtin_amdgcn_mfma_f32_16x16x32_bf16(Ag, By[1][k0], a1, 0, 0, 0);
      a2 = __builtin_amdgcn_mfma_f32_16x16x32_bf16(Ag, By[2][k0], a2, 0, 0, 0);
      a3 = __builtin_amdgcn_mfma_f32_16x16x32_bf16(Ag, By[3][k0], a3, 0, 0, 0);
      a4 = __builtin_amdgcn_mfma_f32_16x16x32_bf16(Ag, By[4][k0], a4, 0, 0, 0);
    }
#pragma unroll
    for (int r = 0; r < 4; ++r) {
      vmax = fmaxf(vmax, fabsf(a0[r]));
      vmax = fmaxf(vmax, fabsf(a1[r]));
      vmax = fmaxf(vmax, fabsf(a2[r]));
      vmax = fmaxf(vmax, fabsf(a3[r]));
      vmax = fmaxf(vmax, fabsf(a4[r]));
    }
  }
  vmax = fmaxf(vmax, __shfl_xor(vmax, 16));
  vmax = fmaxf(vmax, __shfl_xor(vmax, 32));
  if (lane < 16 && vmax > (LAMC - 0.1f)) {
    int idx = atomicAdd(cnt, 1);
    wl[idx] = g * 32 + bhalf * 16 + lane;
  }
}

// ---------------- full ISTA for flagged tiles (fp32, exact; verified R1) ----------
__global__ __launch_bounds__(64) void slow_k(
    const float* __restrict__ vxt, const float* __restrict__ kern,
    const float* __restrict__ kern2, const float* __restrict__ Lbuf,
    const int* __restrict__ cnt, const int* __restrict__ wl,
    float* __restrict__ outp) {
  const int t = threadIdx.x;
  __shared__ float TC[196], TSn[196];
  __shared__ float xs[196];
  __shared__ float t1R[112], t1I[112];
  __shared__ float t2R[112], t2I[112];
  __shared__ float zr[112], zi[112];
  __shared__ float kR[5][112], kI[5][112];
  __shared__ float uu[5][196];
  __shared__ float ss[5][196];
  __shared__ float k2R[112], k2I[112];

  for (int i = t; i < 196; i += 64) {
    int a = i / 14, c = i - (i / 14) * 14;
    int m = (a * c) % 14;
    TC[i] = C14d[m]; TSn[i] = S14d[m];
  }
  const int ntile = *cnt;

  auto rowsFwd = [&](const float* xsrc) {
    for (int i = t; i < 112; i += 64) {
      int r = i >> 3, f = i & 7;
      const float* xp = xsrc + r * 14;
      const float* tc = &TC[f * 14]; const float* tsn = &TSn[f * 14];
      float ar = 0.f, ai = 0.f;
#pragma unroll
      for (int c = 0; c < 14; ++c) { float xv = xp[c]; ar += xv * tc[c]; ai -= xv * tsn[c]; }
      t1R[i] = ar; t1I[i] = ai;
    }
    __syncthreads();
  };
  auto colsFwd = [&](float* oR, float* oI) {
    for (int i = t; i < 112; i += 64) {
      int kr = i >> 3, f = i & 7;
      const float* tc = &TC[kr * 14]; const float* tsn = &TSn[kr * 14];
      float br = 0.f, bi = 0.f;
#pragma unroll
      for (int r = 0; r < 14; ++r) {
        float xr = t1R[r * 8 + f], xi = t1I[r * 8 + f];
        br += tc[r] * xr + tsn[r] * xi;
        bi += tc[r] * xi - tsn[r] * xr;
      }
      oR[i] = br; oI[i] = bi;
    }
    __syncthreads();
  };
  auto colsInv = [&]() {
    for (int i = t; i < 112; i += 64) {
      int r = i >> 3, f = i & 7;
      const float* tc = &TC[r * 14]; const float* tsn = &TSn[r * 14];
      float br = 0.f, bi = 0.f;
#pragma unroll
      for (int kr = 0; kr < 14; ++kr) {
        float xr = t1R[kr * 8 + f], xi = t1I[kr * 8 + f];
        br += tc[kr] * xr - tsn[kr] * xi;
        bi += tc[kr] * xi + tsn[kr] * xr;
      }
      t2R[i] = br; t2I[i] = bi;
    }
    __syncthreads();
  };
  auto rowVal = [&](int r, int c) -> float {
    const float* pR = &t2R[r * 8]; const float* pI = &t2I[r * 8];
    float v = pR[0] + ((c & 1) ? -pR[7] : pR[7]);
    float s2 = 0.f;
#pragma unroll
    for (int f = 1; f < 7; ++f) s2 += pR[f] * TC[f * 14 + c] - pI[f] * TSn[f * 14 + c];
    return (v + 2.f * s2) * (1.0f / 196.0f);
  };

  for (int widx = blockIdx.x; widx < ntile; widx += gridDim.x) {
    const int tile = wl[widx];
    const int g = tile >> 5, b = tile & 31;
    __syncthreads();
    for (int i = t; i < 560; i += 64) {
      int ii = i / 112, p = i - ii * 112;
      const float* kp = kern + ((size_t)g * 5 + ii) * 224 + p * 2;
      kR[ii][p] = kp[0]; kI[ii][p] = kp[1];
    }
    for (int i = t; i < 196; i += 64) xs[i] = vxt[((size_t)b * DIMC + g) * 196 + i];
    for (int i = t; i < 112; i += 64) {
      k2R[i] = kern2[(size_t)g * 224 + i * 2];
      k2I[i] = kern2[(size_t)g * 224 + i * 2 + 1];
    }
    __syncthreads();

    rowsFwd(xs);
    colsFwd(zr, zi);
    for (int ii = 0; ii < 5; ++ii) {
      for (int i = t; i < 112; i += 64) {
        float a = kR[ii][i], b2 = kI[ii][i];
        t1R[i] = a * zr[i] - b2 * zi[i];
        t1I[i] = a * zi[i] + b2 * zr[i];
      }
      __syncthreads();
      colsInv();
      for (int i = t; i < 196; i += 64) uu[ii][i] = rowVal(i / 14, i - (i / 14) * 14);
      __syncthreads();
    }

    const float invL = 1.0f / Lbuf[g];
    const float thr = LAMC * invL;
    {
      float* up = &uu[0][0];
      float* sp = &ss[0][0];
      for (int i = t; i < 980; i += 64) {
        float v = up[i];
        float a = fabsf(v) - LAMC;
        sp[i] = a > 0.f ? copysignf(a, v) : 0.f;
      }
    }
    __syncthreads();

    for (int iter = 0; iter < 4; ++iter) {
      for (int i = t; i < 112; i += 64) { zr[i] = 0.f; zi[i] = 0.f; }
      __syncthreads();
      for (int ii = 0; ii < 5; ++ii) {
        rowsFwd(&ss[ii][0]);
        colsFwd(t2R, t2I);
        for (int i = t; i < 112; i += 64) {
          float a = kR[ii][i], b2 = kI[ii][i];
          zr[i] += a * t2R[i] + b2 * t2I[i];
          zi[i] += a * t2I[i] - b2 * t2R[i];
        }
        __syncthreads();
      }
      if (iter == 3) break;
      for (int ii = 0; ii < 5; ++ii) {
        for (int i = t; i < 112; i += 64) {
          float a = kR[ii][i], b2 = kI[ii][i];
          t1R[i] = a * zr[i] - b2 * zi[i];
          t1I[i] = a * zi[i] + b2 * zr[i];
        }
        __syncthreads();
        colsInv();
        for (int i = t; i < 196; i += 64) {
          float v = rowVal(i / 14, i - (i / 14) * 14);
          float sv = ss[ii][i] - (v - uu[ii][i]) * invL;
          float aa = fabsf(sv) - thr;
          ss[ii][i] = aa > 0.f ? copysignf(aa, sv) : 0.f;
        }
        __syncthreads();
      }
    }

    if (t < 28) {
      int kr = t >> 1, f = (t & 1) * 7;
      int d = kr * 8 + f;
      int srci = ((14 - kr) % 14) * 8 + f;
      float pr = 0.5f * (zr[d] + zr[srci]);
      float pi = 0.5f * (zi[d] - zi[srci]);
      zr[d] = pr; zi[d] = pi;
    }
    __syncthreads();
    for (int i = t; i < 112; i += 64) {
      float a = k2R[i], b2 = k2I[i];
      t1R[i] = a * zr[i] - b2 * zi[i];
      t1I[i] = a * zi[i] + b2 * zr[i];
    }
    __syncthreads();
    colsInv();
    for (int i = t; i < 196; i += 64)
      outp[((size_t)(b * 196 + i)) * DIMC + g] = rowVal(i / 14, i - (i / 14) * 14);
  }
}

// ---------------- launch ----------------
extern "C" void kernel_launch(void* const* d_in, const int* in_sizes, int n_in,
                              void* d_out, int out_size, void* d_ws, size_t ws_size,
                              hipStream_t stream) {
  (void)in_sizes; (void)n_in; (void)out_size;
  const float* x      = (const float*)d_in[0];
  const float* v_w    = (const float*)d_in[1];
  const float* proj_w = (const float*)d_in[2];
  const float* proj_b = (const float*)d_in[3];
  const float* kern   = (const float*)d_in[4];
  const float* kern2  = (const float*)d_in[5];
  const float* n1g    = (const float*)d_in[6];
  const float* n1b    = (const float*)d_in[7];
  const float* n2g    = (const float*)d_in[8];
  const float* n2b    = (const float*)d_in[9];
  const float* fc1w   = (const float*)d_in[10];
  const float* fc1b   = (const float*)d_in[11];
  const float* fc2w   = (const float*)d_in[12];
  const float* fc2b   = (const float*)d_in[13];
  const float* Lb     = (const float*)d_in[14];
  float* out = (float*)d_out;

  char* ws = (char*)d_ws;
  size_t o = 0;
  auto alloc = [&](size_t bytes) { size_t r = o; o += (bytes + 255) & ~(size_t)255; return r; };
  u16*   vwbf   = (u16*)(ws + alloc(589824 * 2));
  u16*   projbf = (u16*)(ws + alloc(589824 * 2));
  u16*   fc1bf  = (u16*)(ws + alloc(2359296 * 2));
  u16*   fc2bf  = (u16*)(ws + alloc(2359296 * 2));
  u16*   Ffb    = (u16*)(ws + alloc(50176 * 2));
  u16*   Gfb    = (u16*)(ws + alloc(46592 * 2));
  float* sc1    = (float*)(ws + alloc(768 * 4));
  float* sh1    = (float*)(ws + alloc(768 * 4));
  float* sc2    = (float*)(ws + alloc(768 * 4));
  float* sh2    = (float*)(ws + alloc(768 * 4));
  float* part   = (float*)(ws + alloc(98 * 768 * 2 * 4));
  int*   cnt    = (int*)(ws + alloc(4));
  int*   wl     = (int*)(ws + alloc(24576 * 4));
  u16*   abf    = (u16*)(ws + alloc((size_t)MTOT * DIMC * 2));
  float* vxt    = (float*)(ws + alloc((size_t)MTOT * DIMC * 4));
  float* newm   = (float*)(ws + alloc((size_t)MTOT * DIMC * 4));
  float* new2   = (float*)(ws + alloc((size_t)MTOT * DIMC * 4));
  u16*   hbf    = (u16*)vxt;   // overlay: h (6272x3072 bf16) over vxt+newm (dead by then)
  if (ws_size < o) return;

  hipMemsetAsync(newm, 0, (size_t)MTOT * DIMC * 4, stream);
  hipMemsetAsync(cnt, 0, 4, stream);

  initfg_k<<<378, 256, 0, stream>>>(Ffb, Gfb);
  cvtw_k<<<5760, 256, 0, stream>>>(v_w, proj_w, fc1w, fc2w, vwbf, projbf, fc1bf, fc2bf);
  cvt4_k<<<4704, 256, 0, stream>>>(x, abf, 1204224);

  // vx = x @ v_w^T, transpose-written as (b, g, n)
  gemm_k<0><<<dim3(6, 49), 256, 0, stream>>>(abf, vwbf, nullptr, nullptr, vxt, DIMC, DIMC);
  // MFMA screen -> worklist (newm stays zero for clean tiles)
  checkmfma_k<<<1536, 64, 0, stream>>>(vxt, kern, Ffb, Gfb, cnt, wl);
  // exact ISTA only for flagged tiles
  slow_k<<<1024, 64, 0, stream>>>(vxt, kern, kern2, Lb, cnt, wl, newm);
  // BN1
  stats_part_k<<<98, 256, 0, stream>>>(newm, part);
  stats_fin_k<<<3, 256, 0, stream>>>(part, n1g, n1b, sc1, sh1);
  bncvt_k<<<4704, 256, 0, stream>>>(newm, sc1, sh1, abf, 1204224);
  // new2 = x + BN1(new) @ proj_w^T + proj_b
  gemm_k<1><<<dim3(6, 49), 256, 0, stream>>>(abf, projbf, proj_b, x, new2, DIMC, DIMC);
  // BN2
  stats_part_k<<<98, 256, 0, stream>>>(new2, part);
  stats_fin_k<<<3, 256, 0, stream>>>(part, n2g, n2b, sc2, sh2);
  bncvt_k<<<4704, 256, 0, stream>>>(new2, sc2, sh2, abf, 1204224);
  // h = gelu(BN2(new2) @ fc1^T + fc1_b)
  gemm_k<2><<<dim3(24, 49), 256, 0, stream>>>(abf, fc1bf, fc1b, nullptr, hbf, HIDC, DIMC);
  // out = new2 + h @ fc2^T + fc2_b
  gemm_k<1><<<dim3(6, 49), 256, 0, stream>>>(hbf, fc2bf, fc2b, new2, out, DIMC, HIDC);
}